// Round 5
// baseline (209.597 us; speedup 1.0000x reference)
//
#include <hip/hip_runtime.h>

typedef unsigned short u16;
typedef unsigned int u32;

typedef __bf16 bf16x8 __attribute__((ext_vector_type(8)));
typedef _Float16 f16x8 __attribute__((ext_vector_type(8)));
typedef float f32x4 __attribute__((ext_vector_type(4)));
typedef float f32x16 __attribute__((ext_vector_type(16)));

typedef __attribute__((address_space(1))) u32 as1_u32;
typedef __attribute__((address_space(3))) u32 as3_u32;

#define EKF 0.18033688011112042f  // 0.125 * log2(e), folded into Q at GEMM1

__device__ __forceinline__ u16 f2bf(float x) {
  u32 u = __float_as_uint(x);
  u = u + 0x7fffu + ((u >> 16) & 1u);   // RNE
  return (u16)(u >> 16);
}
__device__ __forceinline__ u32 pack2(float a, float b) {
  return (u32)f2bf(a) | ((u32)f2bf(b) << 16);
}
__device__ __forceinline__ u32 pkf16(float a, float b) {
  return __builtin_bit_cast(u32, __builtin_amdgcn_cvt_pkrtz(a, b));
}
__device__ __forceinline__ u16 f2h(float a) {
  return (u16)(pkf16(a, a) & 0xffffu);
}
__device__ __forceinline__ void gld_lds16(const u16* g, const u16* l) {
  __builtin_amdgcn_global_load_lds((const as1_u32*)g, (as3_u32*)l, 16, 0, 0);
}

// ---------------- fp32 -> bf16 flat cast ----------------
__global__ void cvt_bf16_kernel(const float* __restrict__ in, u16* __restrict__ out, int n4) {
  int i = blockIdx.x * blockDim.x + threadIdx.x;
  if (i < n4) {
    float4 v = ((const float4*)in)[i];
    uint2 r;
    r.x = pack2(v.x, v.y);
    r.y = pack2(v.z, v.w);
    ((uint2*)out)[i] = r;
  }
}

// ---------------- fp32 [K][N] -> bf16 [N][K] tiled transpose ----------------
__global__ __launch_bounds__(256) void transpose_bf16_tiled(const float* __restrict__ W,
                                                            u16* __restrict__ WT,
                                                            int K, int N) {
  __shared__ float tile[64][65];
  int k0 = blockIdx.x * 64, n0 = blockIdx.y * 64;
  int t = threadIdx.x;
  int r = t >> 4, c4 = (t & 15) * 4;
#pragma unroll
  for (int i = 0; i < 4; ++i) {
    int row = r + i * 16;
    float4 v = *(const float4*)&W[(size_t)(k0 + row) * N + n0 + c4];
    tile[row][c4 + 0] = v.x; tile[row][c4 + 1] = v.y;
    tile[row][c4 + 2] = v.z; tile[row][c4 + 3] = v.w;
  }
  __syncthreads();
#pragma unroll
  for (int i = 0; i < 4; ++i) {
    int n = r + i * 16;
    uint2 o;
    o.x = pack2(tile[c4 + 0][n], tile[c4 + 1][n]);
    o.y = pack2(tile[c4 + 2][n], tile[c4 + 3][n]);
    *(uint2*)&WT[(size_t)(n0 + n) * K + k0 + c4] = o;
  }
}

// ---------------- f16 [4096][1024] -> vt[bh][d][j] tiled transpose ----------------
__global__ __launch_bounds__(256) void transpose_vt_kernel(const u16* __restrict__ vtmp,
                                                           u16* __restrict__ vt) {
  __shared__ u16 t[64 * 71];
  int j0 = blockIdx.x * 64;
  int bh = blockIdx.y;
  int b = bh >> 4, h = bh & 15;
  int tid = threadIdx.x;
  int r = tid >> 2, cs = (tid & 3) * 16;
  const u16* src = vtmp + (size_t)(b * 2048 + j0 + r) * 1024 + h * 64 + cs;
  uint4 a = ((const uint4*)src)[0];
  uint4 c = ((const uint4*)src)[1];
  u16* dst = &t[r * 71 + cs];
  dst[0] = (u16)a.x; dst[1] = (u16)(a.x >> 16); dst[2] = (u16)a.y; dst[3] = (u16)(a.y >> 16);
  dst[4] = (u16)a.z; dst[5] = (u16)(a.z >> 16); dst[6] = (u16)a.w; dst[7] = (u16)(a.w >> 16);
  dst[8] = (u16)c.x; dst[9] = (u16)(c.x >> 16); dst[10] = (u16)c.y; dst[11] = (u16)(c.y >> 16);
  dst[12] = (u16)c.z; dst[13] = (u16)(c.z >> 16); dst[14] = (u16)c.w; dst[15] = (u16)(c.w >> 16);
  __syncthreads();
  int d = tid >> 2, jseg = (tid & 3) * 16;
  u32 w[8];
#pragma unroll
  for (int i = 0; i < 8; ++i) {
    u32 lo = t[(jseg + 2 * i) * 71 + d];
    u32 hi = t[(jseg + 2 * i + 1) * 71 + d];
    w[i] = lo | (hi << 16);
  }
  u16* out = vt + (size_t)(bh * 64 + d) * 2048 + j0 + jseg;
  ((uint4*)out)[0] = make_uint4(w[0], w[1], w[2], w[3]);
  ((uint4*)out)[1] = make_uint4(w[4], w[5], w[6], w[7]);
}

// ---------------- bf16 GEMM: C[M,N] = A[M,K] * BT[N,K]^T ----------------
template <int OUT_MODE, int BN>
__global__ __launch_bounds__(256) void gemm_bt_kernel(const u16* __restrict__ A,
                                                      const u16* __restrict__ BT,
                                                      void* __restrict__ Cv,
                                                      u16* __restrict__ VT,
                                                      int M, int N, int K) {
  const int NF = (BN == 128) ? 4 : 2;
  __shared__ __attribute__((aligned(16))) u16 sA[128 * 32];
  __shared__ __attribute__((aligned(16))) u16 sB[BN * 32];
  const int tid = threadIdx.x;
  const int wave = tid >> 6;
  const int lane = tid & 63;
  const int bm = blockIdx.y * 128;
  const int bn = blockIdx.x * BN;
  const int wm = (wave >> 1) * 64;
  const int wn = (wave & 1) * (BN / 2);
  const int lr = lane & 15;
  const int kg = lane >> 4;

  const int srow = tid >> 2;
  const int scol = (tid & 3) * 8;
  const u16* pa0 = A + (size_t)(bm + srow) * K + scol;
  const u16* pa1 = pa0 + (size_t)64 * K;
  const u16* pb0 = BT + (size_t)(bn + srow) * K + scol;
  const u16* pb1 = pb0 + (size_t)64 * K;
  const u16* la = sA + wave * 512;
  const u16* lb = sB + wave * 512;

  f32x4 acc[4][NF];
#pragma unroll
  for (int i = 0; i < 4; i++)
#pragma unroll
    for (int j = 0; j < NF; j++) {
      f32x4 z = {0.f, 0.f, 0.f, 0.f};
      acc[i][j] = z;
    }

  for (int k0 = 0; k0 < K; k0 += 32) {
    __syncthreads();
    gld_lds16(pa0 + k0, la);
    gld_lds16(pa1 + k0, la + 2048);
    gld_lds16(pb0 + k0, lb);
    if (BN == 128) gld_lds16(pb1 + k0, lb + 2048);
    __syncthreads();
    bf16x8 af[4], bfr[NF];
#pragma unroll
    for (int mi = 0; mi < 4; mi++)
      af[mi] = *(const bf16x8*)(sA + (wm + mi * 16 + lr) * 32 + kg * 8);
#pragma unroll
    for (int ni = 0; ni < NF; ni++)
      bfr[ni] = *(const bf16x8*)(sB + (wn + ni * 16 + lr) * 32 + kg * 8);
#pragma unroll
    for (int mi = 0; mi < 4; mi++)
#pragma unroll
      for (int ni = 0; ni < NF; ni++)
        acc[mi][ni] = __builtin_amdgcn_mfma_f32_16x16x32_bf16(af[mi], bfr[ni], acc[mi][ni], 0, 0, 0);
  }

#pragma unroll
  for (int mi = 0; mi < 4; mi++)
#pragma unroll
    for (int ni = 0; ni < NF; ni++) {
      int c = bn + wn + ni * 16 + lr;
      int r0 = bm + wm + mi * 16 + kg * 4;
      if (OUT_MODE == 0) {
#pragma unroll
        for (int rr = 0; rr < 4; rr++)
          ((float*)Cv)[(size_t)(r0 + rr) * N + c] = acc[mi][ni][rr];
      } else {
        if (c < 1024) {
          u16* qkp = (u16*)Cv;
#pragma unroll
          for (int rr = 0; rr < 4; rr++)
            qkp[(size_t)(r0 + rr) * 2048 + c] = f2bf(acc[mi][ni][rr] * EKF);
        } else if (c < 2048) {
          u16* qkp = (u16*)Cv;
#pragma unroll
          for (int rr = 0; rr < 4; rr++)
            qkp[(size_t)(r0 + rr) * 2048 + c] = f2bf(acc[mi][ni][rr]);
        } else {
          int cc = c - 2048;
#pragma unroll
          for (int rr = 0; rr < 4; rr++)
            VT[(size_t)(r0 + rr) * 1024 + cc] = f2h(acc[mi][ni][rr]);
        }
      }
    }
}

// ---------------- MFMA flash attention, 32x32 tiles, swizzled LDS ----------------
// qk: [4096][2048] bf16 (cols 0:1024 pre-scaled q, 1024:2048 k; head h at h*64)
// vt: [32][64][2048] f16 (vt[bh][d][j]); out: [4096][1024] bf16
// 512 blocks (heavy-first): q-tile 128 per block, wave w owns q [q0+32w, +32).
// S^T via mfma_f32_32x32x16_bf16 (A=K rows j, B=Q cols q); P -> per-wave LDS;
// O^T via mfma_f32_32x32x16_f16 (A=Vt rows d, B=P cols q).
// K/V LDS tiles [64 r][64 c] with 16B-chunk XOR swizzle (chunk ^= r&7):
// frag reads hit 8 uniform bank-start classes (min-cycle b128).
__global__ __launch_bounds__(256, 3) void attn_mfma_kernel(const u16* __restrict__ qk,
                                                           const u16* __restrict__ vt,
                                                           u16* __restrict__ out) {
  __shared__ __attribute__((aligned(16))) u16 sK[64 * 64];
  __shared__ __attribute__((aligned(16))) u16 sV[64 * 64];
  __shared__ __attribute__((aligned(16))) u16 sP[4][32 * 48];

  const int tid = threadIdx.x;
  const int wave = tid >> 6;
  const int lane = tid & 63;
  const int lq = lane & 31;   // q col (B n), also j/d row (A m)
  const int g = lane >> 5;    // half-wave group
  const int l7 = lane & 7;    // swizzle key for A-frag rows (row&7 == lane&7)

  int idx = blockIdx.x;
  int qi = 15 - (idx >> 5);   // heavy q-tiles first
  int bh = idx & 31;
  int b = bh >> 4, h = bh & 15;
  int q0 = qi * 128;

  const u16* qbase = qk + (size_t)b * 2048 * 2048 + h * 64;
  const u16* kbase = qbase + 1024;
  const u16* vbase = vt + (size_t)bh * 64 * 2048;
  u16* obase = out + (size_t)b * 2048 * 1024 + h * 64;

  // Q fragments straight from global (4 x b128 per lane, once)
  const int qcol = q0 + wave * 32 + lq;
  bf16x8 qf[4];
  {
    const u16* qrow = qbase + (size_t)qcol * 2048;
#pragma unroll
    for (int ks = 0; ks < 4; ++ks)
      qf[ks] = *(const bf16x8*)(qrow + ks * 16 + g * 8);
  }

  // lane-constant diagonal mask: j_local(reg) <= q_local
  bool dmask[16];
#pragma unroll
  for (int a = 0; a < 16; ++a)
    dmask[a] = ((a & 3) + 8 * (a >> 2) + 4 * g) <= lq;

  f32x16 oacc[2];
#pragma unroll
  for (int i = 0; i < 16; ++i) { oacc[0][i] = 0.f; oacc[1][i] = 0.f; }
  float lsum = 0.f;

  // staging assignment (block-wide): row r = tid>>2, 32B col segment (tid&3)
  const int sr = tid >> 2;
  const int se = (tid & 3) * 16;           // elem offset in row
  const int sc0 = (tid & 3) * 2;           // chunk index (16B chunks)
  const int sr7 = sr & 7;
  u16* const skw0 = sK + sr * 64 + ((sc0 ^ sr7) * 8);
  u16* const skw1 = sK + sr * 64 + (((sc0 + 1) ^ sr7) * 8);
  u16* const svw0 = sV + sr * 64 + ((sc0 ^ sr7) * 8);
  u16* const svw1 = sV + sr * 64 + (((sc0 + 1) ^ sr7) * 8);

  u16* const sPw = sP[wave];
  const int smax = wave + 4 * qi;  // this wave's diagonal subtile index

  const int nrounds = 2 * qi + 2;
  for (int t = 0; t < nrounds; ++t) {
    int j0 = t * 64;
    __syncthreads();
    {
      const u16* kg_ = kbase + (size_t)(j0 + sr) * 2048 + se;
      uint4 ka = ((const uint4*)kg_)[0];
      uint4 kb = ((const uint4*)kg_)[1];
      const u16* vg = vbase + (size_t)sr * 2048 + j0 + se;
      uint4 va = ((const uint4*)vg)[0];
      uint4 vb = ((const uint4*)vg)[1];
      *(uint4*)skw0 = ka;
      *(uint4*)skw1 = kb;
      *(uint4*)svw0 = va;
      *(uint4*)svw1 = vb;
    }
    __syncthreads();

#pragma unroll
    for (int jt = 0; jt < 2; ++jt) {
      int s = 2 * t + jt;
      if (s > smax) continue;  // wave-uniform skip (fully masked)

      // S^T subtile: 32 j x 32 q
      f32x16 st;
#pragma unroll
      for (int i = 0; i < 16; ++i) st[i] = 0.f;
#pragma unroll
      for (int ks = 0; ks < 4; ++ks) {
        bf16x8 kf = *(const bf16x8*)(sK + (jt * 32 + lq) * 64 + (((ks * 2 + g) ^ l7) * 8));
        st = __builtin_amdgcn_mfma_f32_32x32x16_bf16(kf, qf[ks], st, 0, 0, 0);
      }

      float p[16];
      if (s == smax) {
#pragma unroll
        for (int a = 0; a < 16; ++a) p[a] = dmask[a] ? exp2f(st[a]) : 0.f;
      } else {
#pragma unroll
        for (int a = 0; a < 16; ++a) p[a] = exp2f(st[a]);
      }
#pragma unroll
      for (int a = 0; a < 16; ++a) lsum += p[a];

      // P store: row q=lq (48-u16 stride), j_local = 8*tq + 4*g + 0..3
      u16* pwv = sPw + lq * 48 + g * 4;
#pragma unroll
      for (int tq = 0; tq < 4; ++tq)
        *(uint2*)(pwv + tq * 8) =
            make_uint2(pkf16(p[4 * tq + 0], p[4 * tq + 1]),
                       pkf16(p[4 * tq + 2], p[4 * tq + 3]));

      asm volatile("" ::: "memory");  // P writes precede P-frag reads (same wave)

#pragma unroll
      for (int ks = 0; ks < 2; ++ks) {
        f16x8 pf = *(const f16x8*)(sPw + lq * 48 + ks * 16 + g * 8);
#pragma unroll
        for (int dt = 0; dt < 2; ++dt) {
          f16x8 vf = *(const f16x8*)(sV + (dt * 32 + lq) * 64 +
                                     (((jt * 4 + ks * 2 + g) ^ l7) * 8));
          oacc[dt] = __builtin_amdgcn_mfma_f32_32x32x16_f16(vf, pf, oacc[dt], 0, 0, 0);
        }
      }
    }
  }

  // l: combine the two half-wave j-partitions (lanes L and L^32 share q)
  lsum += __shfl_xor(lsum, 32);
  float inv = 1.0f / lsum;

  // epilogue: O^T[d][q] -> out[q][d]; reg a -> d = dt*32 + 8*(a>>2) + 4*g + (a&3)
  u16* orow = obase + (size_t)qcol * 1024;
#pragma unroll
  for (int dt = 0; dt < 2; ++dt)
#pragma unroll
    for (int tq = 0; tq < 4; ++tq) {
      int d = dt * 32 + 8 * tq + 4 * g;
      uint2 o2 = make_uint2(pack2(oacc[dt][4 * tq + 0] * inv, oacc[dt][4 * tq + 1] * inv),
                            pack2(oacc[dt][4 * tq + 2] * inv, oacc[dt][4 * tq + 3] * inv));
      *(uint2*)(orow + d) = o2;
    }
}

// ---------------- launch ----------------
extern "C" void kernel_launch(void* const* d_in, const int* in_sizes, int n_in,
                              void* d_out, int out_size, void* d_ws, size_t ws_size,
                              hipStream_t stream) {
  const float* x = (const float*)d_in[0];      // [2,2048,1024]
  const float* w_qkv = (const float*)d_in[1];  // [1024,3072]
  const float* w_out = (const float*)d_in[2];  // [1024,1024]
  float* out = (float*)d_out;                  // [2,2048,1024] fp32

  char* ws = (char*)d_ws;
  u16* xb    = (u16*)(ws);                //  8 MB: x bf16 [4096,1024]
  u16* wqkvT = (u16*)(ws + (8u << 20));   //  6 MB: w_qkv^T bf16 [3072,1024]
  u16* woutT = (u16*)(ws + (14u << 20));  //  2 MB: w_out^T bf16 [1024,1024]
  u16* qkb   = (u16*)(ws + (16u << 20));  // 16 MB: q|k bf16 [4096,2048]
  u16* vtb   = (u16*)(ws + (32u << 20));  //  8 MB: V^T f16 [32,64,2048]
  u16* vtmp  = (u16*)(ws + (40u << 20));  //  8 MB: v f16 [4096,1024] (dead after
  u16* attn  = (u16*)(ws + (40u << 20));  //        transpose_vt; region reused)

  cvt_bf16_kernel<<<4096, 256, 0, stream>>>(x, xb, 4194304 / 4);
  transpose_bf16_tiled<<<dim3(16, 48), 256, 0, stream>>>(w_qkv, wqkvT, 1024, 3072);
  transpose_bf16_tiled<<<dim3(16, 16), 256, 0, stream>>>(w_out, woutT, 1024, 1024);

  gemm_bt_kernel<2, 128><<<dim3(3072 / 128, 4096 / 128), 256, 0, stream>>>(
      xb, wqkvT, (void*)qkb, vtmp, 4096, 3072, 1024);

  transpose_vt_kernel<<<dim3(32, 32), 256, 0, stream>>>(vtmp, vtb);

  attn_mfma_kernel<<<512, 256, 0, stream>>>(qkb, vtb, attn);

  gemm_bt_kernel<0, 64><<<dim3(1024 / 64, 4096 / 128), 256, 0, stream>>>(
      attn, woutT, (void*)out, nullptr, 4096, 1024, 1024);
}

// Round 6
// 209.340 us; speedup vs baseline: 1.0012x; 1.0012x over previous
//
#include <hip/hip_runtime.h>

typedef unsigned short u16;
typedef unsigned int u32;

typedef __bf16 bf16x8 __attribute__((ext_vector_type(8)));
typedef _Float16 f16x8 __attribute__((ext_vector_type(8)));
typedef float f32x4 __attribute__((ext_vector_type(4)));
typedef float f32x16 __attribute__((ext_vector_type(16)));

typedef __attribute__((address_space(1))) u32 as1_u32;
typedef __attribute__((address_space(3))) u32 as3_u32;

#define EKF 0.18033688011112042f  // 0.125 * log2(e), folded into Q at GEMM1

__device__ __forceinline__ u16 f2bf(float x) {
  u32 u = __float_as_uint(x);
  u = u + 0x7fffu + ((u >> 16) & 1u);   // RNE
  return (u16)(u >> 16);
}
__device__ __forceinline__ u32 pack2(float a, float b) {
  return (u32)f2bf(a) | ((u32)f2bf(b) << 16);
}
__device__ __forceinline__ u32 pkf16(float a, float b) {
  return __builtin_bit_cast(u32, __builtin_amdgcn_cvt_pkrtz(a, b));
}
__device__ __forceinline__ u16 f2h(float a) {
  return (u16)(pkf16(a, a) & 0xffffu);
}
__device__ __forceinline__ void gld_lds16(const u16* g, const u16* l) {
  __builtin_amdgcn_global_load_lds((const as1_u32*)g, (as3_u32*)l, 16, 0, 0);
}

// ---------------- fp32 -> bf16 flat cast ----------------
__global__ void cvt_bf16_kernel(const float* __restrict__ in, u16* __restrict__ out, int n4) {
  int i = blockIdx.x * blockDim.x + threadIdx.x;
  if (i < n4) {
    float4 v = ((const float4*)in)[i];
    uint2 r;
    r.x = pack2(v.x, v.y);
    r.y = pack2(v.z, v.w);
    ((uint2*)out)[i] = r;
  }
}

// ---------------- fp32 [K][N] -> bf16 [N][K] tiled transpose ----------------
__global__ __launch_bounds__(256) void transpose_bf16_tiled(const float* __restrict__ W,
                                                            u16* __restrict__ WT,
                                                            int K, int N) {
  __shared__ float tile[64][65];
  int k0 = blockIdx.x * 64, n0 = blockIdx.y * 64;
  int t = threadIdx.x;
  int r = t >> 4, c4 = (t & 15) * 4;
#pragma unroll
  for (int i = 0; i < 4; ++i) {
    int row = r + i * 16;
    float4 v = *(const float4*)&W[(size_t)(k0 + row) * N + n0 + c4];
    tile[row][c4 + 0] = v.x; tile[row][c4 + 1] = v.y;
    tile[row][c4 + 2] = v.z; tile[row][c4 + 3] = v.w;
  }
  __syncthreads();
#pragma unroll
  for (int i = 0; i < 4; ++i) {
    int n = r + i * 16;
    uint2 o;
    o.x = pack2(tile[c4 + 0][n], tile[c4 + 1][n]);
    o.y = pack2(tile[c4 + 2][n], tile[c4 + 3][n]);
    *(uint2*)&WT[(size_t)(n0 + n) * K + k0 + c4] = o;
  }
}

// ---------------- f16 [4096][1024] -> vt[bh][d][j] tiled transpose ----------------
__global__ __launch_bounds__(256) void transpose_vt_kernel(const u16* __restrict__ vtmp,
                                                           u16* __restrict__ vt) {
  __shared__ u16 t[64 * 71];
  int j0 = blockIdx.x * 64;
  int bh = blockIdx.y;
  int b = bh >> 4, h = bh & 15;
  int tid = threadIdx.x;
  int r = tid >> 2, cs = (tid & 3) * 16;
  const u16* src = vtmp + (size_t)(b * 2048 + j0 + r) * 1024 + h * 64 + cs;
  uint4 a = ((const uint4*)src)[0];
  uint4 c = ((const uint4*)src)[1];
  u16* dst = &t[r * 71 + cs];
  dst[0] = (u16)a.x; dst[1] = (u16)(a.x >> 16); dst[2] = (u16)a.y; dst[3] = (u16)(a.y >> 16);
  dst[4] = (u16)a.z; dst[5] = (u16)(a.z >> 16); dst[6] = (u16)a.w; dst[7] = (u16)(a.w >> 16);
  dst[8] = (u16)c.x; dst[9] = (u16)(c.x >> 16); dst[10] = (u16)c.y; dst[11] = (u16)(c.y >> 16);
  dst[12] = (u16)c.z; dst[13] = (u16)(c.z >> 16); dst[14] = (u16)c.w; dst[15] = (u16)(c.w >> 16);
  __syncthreads();
  int d = tid >> 2, jseg = (tid & 3) * 16;
  u32 w[8];
#pragma unroll
  for (int i = 0; i < 8; ++i) {
    u32 lo = t[(jseg + 2 * i) * 71 + d];
    u32 hi = t[(jseg + 2 * i + 1) * 71 + d];
    w[i] = lo | (hi << 16);
  }
  u16* out = vt + (size_t)(bh * 64 + d) * 2048 + j0 + jseg;
  ((uint4*)out)[0] = make_uint4(w[0], w[1], w[2], w[3]);
  ((uint4*)out)[1] = make_uint4(w[4], w[5], w[6], w[7]);
}

// ---------------- bf16 GEMM: C[M,N] = A[M,K] * BT[N,K]^T ----------------
template <int OUT_MODE, int BN>
__global__ __launch_bounds__(256) void gemm_bt_kernel(const u16* __restrict__ A,
                                                      const u16* __restrict__ BT,
                                                      void* __restrict__ Cv,
                                                      u16* __restrict__ VT,
                                                      int M, int N, int K) {
  const int NF = (BN == 128) ? 4 : 2;
  __shared__ __attribute__((aligned(16))) u16 sA[128 * 32];
  __shared__ __attribute__((aligned(16))) u16 sB[BN * 32];
  const int tid = threadIdx.x;
  const int wave = tid >> 6;
  const int lane = tid & 63;
  const int bm = blockIdx.y * 128;
  const int bn = blockIdx.x * BN;
  const int wm = (wave >> 1) * 64;
  const int wn = (wave & 1) * (BN / 2);
  const int lr = lane & 15;
  const int kg = lane >> 4;

  const int srow = tid >> 2;
  const int scol = (tid & 3) * 8;
  const u16* pa0 = A + (size_t)(bm + srow) * K + scol;
  const u16* pa1 = pa0 + (size_t)64 * K;
  const u16* pb0 = BT + (size_t)(bn + srow) * K + scol;
  const u16* pb1 = pb0 + (size_t)64 * K;
  const u16* la = sA + wave * 512;
  const u16* lb = sB + wave * 512;

  f32x4 acc[4][NF];
#pragma unroll
  for (int i = 0; i < 4; i++)
#pragma unroll
    for (int j = 0; j < NF; j++) {
      f32x4 z = {0.f, 0.f, 0.f, 0.f};
      acc[i][j] = z;
    }

  for (int k0 = 0; k0 < K; k0 += 32) {
    __syncthreads();
    gld_lds16(pa0 + k0, la);
    gld_lds16(pa1 + k0, la + 2048);
    gld_lds16(pb0 + k0, lb);
    if (BN == 128) gld_lds16(pb1 + k0, lb + 2048);
    __syncthreads();
    bf16x8 af[4], bfr[NF];
#pragma unroll
    for (int mi = 0; mi < 4; mi++)
      af[mi] = *(const bf16x8*)(sA + (wm + mi * 16 + lr) * 32 + kg * 8);
#pragma unroll
    for (int ni = 0; ni < NF; ni++)
      bfr[ni] = *(const bf16x8*)(sB + (wn + ni * 16 + lr) * 32 + kg * 8);
#pragma unroll
    for (int mi = 0; mi < 4; mi++)
#pragma unroll
      for (int ni = 0; ni < NF; ni++)
        acc[mi][ni] = __builtin_amdgcn_mfma_f32_16x16x32_bf16(af[mi], bfr[ni], acc[mi][ni], 0, 0, 0);
  }

#pragma unroll
  for (int mi = 0; mi < 4; mi++)
#pragma unroll
    for (int ni = 0; ni < NF; ni++) {
      int c = bn + wn + ni * 16 + lr;
      int r0 = bm + wm + mi * 16 + kg * 4;
      if (OUT_MODE == 0) {
#pragma unroll
        for (int rr = 0; rr < 4; rr++)
          ((float*)Cv)[(size_t)(r0 + rr) * N + c] = acc[mi][ni][rr];
      } else {
        if (c < 1024) {
          u16* qkp = (u16*)Cv;
#pragma unroll
          for (int rr = 0; rr < 4; rr++)
            qkp[(size_t)(r0 + rr) * 2048 + c] = f2bf(acc[mi][ni][rr] * EKF);
        } else if (c < 2048) {
          u16* qkp = (u16*)Cv;
#pragma unroll
          for (int rr = 0; rr < 4; rr++)
            qkp[(size_t)(r0 + rr) * 2048 + c] = f2bf(acc[mi][ni][rr]);
        } else {
          int cc = c - 2048;
#pragma unroll
          for (int rr = 0; rr < 4; rr++)
            VT[(size_t)(r0 + rr) * 1024 + cc] = f2h(acc[mi][ni][rr]);
        }
      }
    }
}

// ---------------- MFMA flash attention, 32x32 tiles, 2-wave blocks ----------------
// qk: [4096][2048] bf16 (cols 0:1024 pre-scaled q, 1024:2048 k; head h at h*64)
// vt: [32][64][2048] f16 (vt[bh][d][j]); out: [4096][1024] bf16
// 1024 blocks x 128 thr (heavy-first): q-tile 64, wave w owns q [q0+32w, +32).
// LDS 22.5 KB -> 7 blocks/CU (14 waves) for latency hiding.
// Math identical to the verified r5 kernel (32x32 MFMA, XOR-swizzled K/V tiles).
__global__ __launch_bounds__(128, 4) void attn_mfma_kernel(const u16* __restrict__ qk,
                                                           const u16* __restrict__ vt,
                                                           u16* __restrict__ out) {
  __shared__ __attribute__((aligned(16))) u16 sK[64 * 64];
  __shared__ __attribute__((aligned(16))) u16 sV[64 * 64];
  __shared__ __attribute__((aligned(16))) u16 sP[2][32 * 48];

  const int tid = threadIdx.x;
  const int wave = tid >> 6;
  const int lane = tid & 63;
  const int lq = lane & 31;   // q col (B n), also j/d row (A m)
  const int g = lane >> 5;    // half-wave group
  const int l7 = lane & 7;    // swizzle key (row&7 == lane&7 for frag rows)

  int idx = blockIdx.x;
  int qi = 31 - (idx >> 5);   // heavy q-tiles first
  int bh = idx & 31;
  int b = bh >> 4, h = bh & 15;
  int q0 = qi * 64;

  const u16* qbase = qk + (size_t)b * 2048 * 2048 + h * 64;
  const u16* kbase = qbase + 1024;
  const u16* vbase = vt + (size_t)bh * 64 * 2048;
  u16* obase = out + (size_t)b * 2048 * 1024 + h * 64;

  // Q fragments straight from global (4 x b128 per lane, once)
  const int qcol = q0 + wave * 32 + lq;
  bf16x8 qf[4];
  {
    const u16* qrow = qbase + (size_t)qcol * 2048;
#pragma unroll
    for (int ks = 0; ks < 4; ++ks)
      qf[ks] = *(const bf16x8*)(qrow + ks * 16 + g * 8);
  }

  // lane-constant diagonal mask: j_local(reg) <= q_local
  bool dmask[16];
#pragma unroll
  for (int a = 0; a < 16; ++a)
    dmask[a] = ((a & 3) + 8 * (a >> 2) + 4 * g) <= lq;

  f32x16 oacc[2];
#pragma unroll
  for (int i = 0; i < 16; ++i) { oacc[0][i] = 0.f; oacc[1][i] = 0.f; }
  float lsum = 0.f;

  // staging: thread t -> row sr = t>>1, 64B half (t&1), 4 swizzled 16B chunks
  const int sr = tid >> 1;
  const int se = (tid & 1) * 32;   // elem offset in row
  const int sc0 = (tid & 1) * 4;   // first chunk index
  const int sr7 = sr & 7;

  u16* const sPw = sP[wave];
  const int smax = 2 * qi + wave;  // this wave's diagonal 32-j subtile index

  const int nrounds = qi + 1;
  for (int t = 0; t < nrounds; ++t) {
    int j0 = t * 64;
    __syncthreads();
    {
      const u16* kg_ = kbase + (size_t)(j0 + sr) * 2048 + se;
      const u16* vg = vbase + (size_t)sr * 2048 + j0 + se;
      uint4 kc[4], vc[4];
#pragma unroll
      for (int i = 0; i < 4; ++i) kc[i] = ((const uint4*)kg_)[i];
#pragma unroll
      for (int i = 0; i < 4; ++i) vc[i] = ((const uint4*)vg)[i];
#pragma unroll
      for (int i = 0; i < 4; ++i) {
        int ch = ((sc0 + i) ^ sr7) * 8;
        *(uint4*)(sK + sr * 64 + ch) = kc[i];
        *(uint4*)(sV + sr * 64 + ch) = vc[i];
      }
    }
    __syncthreads();

#pragma unroll
    for (int jt = 0; jt < 2; ++jt) {
      int s = 2 * t + jt;
      if (s > smax) continue;  // wave-uniform skip (fully masked)

      // S^T subtile: 32 j x 32 q
      f32x16 st;
#pragma unroll
      for (int i = 0; i < 16; ++i) st[i] = 0.f;
#pragma unroll
      for (int ks = 0; ks < 4; ++ks) {
        bf16x8 kf = *(const bf16x8*)(sK + (jt * 32 + lq) * 64 + (((ks * 2 + g) ^ l7) * 8));
        st = __builtin_amdgcn_mfma_f32_32x32x16_bf16(kf, qf[ks], st, 0, 0, 0);
      }

      float p[16];
      if (s == smax) {
#pragma unroll
        for (int a = 0; a < 16; ++a) p[a] = dmask[a] ? exp2f(st[a]) : 0.f;
      } else {
#pragma unroll
        for (int a = 0; a < 16; ++a) p[a] = exp2f(st[a]);
      }
#pragma unroll
      for (int a = 0; a < 16; ++a) lsum += p[a];

      // P store: row q=lq (48-u16 stride), j_local = 8*tq + 4*g + 0..3
      u16* pwv = sPw + lq * 48 + g * 4;
#pragma unroll
      for (int tq = 0; tq < 4; ++tq)
        *(uint2*)(pwv + tq * 8) =
            make_uint2(pkf16(p[4 * tq + 0], p[4 * tq + 1]),
                       pkf16(p[4 * tq + 2], p[4 * tq + 3]));

      asm volatile("" ::: "memory");  // P writes precede P-frag reads (same wave)

#pragma unroll
      for (int ks = 0; ks < 2; ++ks) {
        f16x8 pf = *(const f16x8*)(sPw + lq * 48 + ks * 16 + g * 8);
#pragma unroll
        for (int dt = 0; dt < 2; ++dt) {
          f16x8 vf = *(const f16x8*)(sV + (dt * 32 + lq) * 64 +
                                     (((jt * 4 + ks * 2 + g) ^ l7) * 8));
          oacc[dt] = __builtin_amdgcn_mfma_f32_32x32x16_f16(vf, pf, oacc[dt], 0, 0, 0);
        }
      }
    }
  }

  // l: combine the two half-wave j-partitions (lanes L and L^32 share q)
  lsum += __shfl_xor(lsum, 32);
  float inv = 1.0f / lsum;

  // epilogue: O^T[d][q] -> out[q][d]; reg a -> d = dt*32 + 8*(a>>2) + 4*g + (a&3)
  u16* orow = obase + (size_t)qcol * 1024;
#pragma unroll
  for (int dt = 0; dt < 2; ++dt)
#pragma unroll
    for (int tq = 0; tq < 4; ++tq) {
      int d = dt * 32 + 8 * tq + 4 * g;
      uint2 o2 = make_uint2(pack2(oacc[dt][4 * tq + 0] * inv, oacc[dt][4 * tq + 1] * inv),
                            pack2(oacc[dt][4 * tq + 2] * inv, oacc[dt][4 * tq + 3] * inv));
      *(uint2*)(orow + d) = o2;
    }
}

// ---------------- launch ----------------
extern "C" void kernel_launch(void* const* d_in, const int* in_sizes, int n_in,
                              void* d_out, int out_size, void* d_ws, size_t ws_size,
                              hipStream_t stream) {
  const float* x = (const float*)d_in[0];      // [2,2048,1024]
  const float* w_qkv = (const float*)d_in[1];  // [1024,3072]
  const float* w_out = (const float*)d_in[2];  // [1024,1024]
  float* out = (float*)d_out;                  // [2,2048,1024] fp32

  char* ws = (char*)d_ws;
  u16* xb    = (u16*)(ws);                //  8 MB: x bf16 [4096,1024]
  u16* wqkvT = (u16*)(ws + (8u << 20));   //  6 MB: w_qkv^T bf16 [3072,1024]
  u16* woutT = (u16*)(ws + (14u << 20));  //  2 MB: w_out^T bf16 [1024,1024]
  u16* qkb   = (u16*)(ws + (16u << 20));  // 16 MB: q|k bf16 [4096,2048]
  u16* vtb   = (u16*)(ws + (32u << 20));  //  8 MB: V^T f16 [32,64,2048]
  u16* vtmp  = (u16*)(ws + (40u << 20));  //  8 MB: v f16 [4096,1024] (dead after
  u16* attn  = (u16*)(ws + (40u << 20));  //        transpose_vt; region reused)

  cvt_bf16_kernel<<<4096, 256, 0, stream>>>(x, xb, 4194304 / 4);
  transpose_bf16_tiled<<<dim3(16, 48), 256, 0, stream>>>(w_qkv, wqkvT, 1024, 3072);
  transpose_bf16_tiled<<<dim3(16, 16), 256, 0, stream>>>(w_out, woutT, 1024, 1024);

  gemm_bt_kernel<2, 128><<<dim3(3072 / 128, 4096 / 128), 256, 0, stream>>>(
      xb, wqkvT, (void*)qkb, vtmp, 4096, 3072, 1024);

  transpose_vt_kernel<<<dim3(32, 32), 256, 0, stream>>>(vtmp, vtb);

  attn_mfma_kernel<<<1024, 128, 0, stream>>>(qkb, vtb, attn);

  gemm_bt_kernel<0, 64><<<dim3(1024 / 64, 4096 / 128), 256, 0, stream>>>(
      attn, woutT, (void*)out, nullptr, 4096, 1024, 1024);
}